// Round 1
// baseline (7286.385 us; speedup 1.0000x reference)
//
#include <hip/hip_runtime.h>
#include <hip/hip_bf16.h>

#define LL 1568
#define EE 384
#define DD 768
#define BB 4

typedef float f32x4 __attribute__((ext_vector_type(4)));
typedef unsigned short u16x4 __attribute__((ext_vector_type(4)));
typedef __bf16 bf16x8 __attribute__((ext_vector_type(8)));

__device__ inline unsigned short f2bf(float f) {
    unsigned int u = __builtin_bit_cast(unsigned int, f);
    u += 0x7fffu + ((u >> 16) & 1u);
    return (unsigned short)(u >> 16);
}

__device__ inline float silu_f(float v) { return v / (1.f + __expf(-v)); }

// ---------------- patch extraction ----------------
__global__ __launch_bounds__(256) void k_patch(const float* __restrict__ x, float* __restrict__ patches) {
    int bid = blockIdx.x;
    int b = bid / LL, rr = bid % LL, t = rr / 196, pp = rr % 196, hp = pp / 14, wp = pp % 14;
    for (int k = threadIdx.x; k < 768; k += 256) {
        int c = k >> 8, rem = k & 255, i = rem >> 4, j = rem & 15;
        patches[(size_t)bid * 768 + k] =
            x[(((size_t)(b * 3 + c) * 8 + t) * 224 + hp * 16 + i) * 224 + wp * 16 + j];
    }
}

// ---------------- GEMM: C[m][n] = sum_k A[m][k] * W[n][k]  (bf16 MFMA) ----------------
// EPI: 0 none, 1 patch-add (bias+pos+tpos), 2 bias+relu
template <int EPI, bool ASUM>
__global__ __launch_bounds__(256) void k_gemm(
    const float* __restrict__ A, const float* __restrict__ A2,
    const float* __restrict__ W, float* __restrict__ C,
    int K, int ldc,
    const float* __restrict__ bias, const float* __restrict__ pos, const float* __restrict__ tpos) {
    const int tid = threadIdx.x;
    const int m0 = blockIdx.y * 128;
    const int n0 = blockIdx.x * 128;
    __shared__ unsigned short As[128 * 40];
    __shared__ unsigned short Ws[128 * 40];
    const int r0 = tid >> 3;  // 0..31
    const int kq = tid & 7;   // 0..7 (float4 index in the 32-wide k tile)

    f32x4 acc[4][4];
#pragma unroll
    for (int mi = 0; mi < 4; mi++)
#pragma unroll
        for (int ni = 0; ni < 4; ni++) acc[mi][ni] = (f32x4){0.f, 0.f, 0.f, 0.f};

    const int lane = tid & 63;
    const int wv = tid >> 6;
    const int wm = (wv & 1) << 6;
    const int wn = (wv >> 1) << 6;
    const int lr = lane & 15;
    const int kg = lane >> 4;

    f32x4 ar[4], wr_[4];
    auto loadTiles = [&](int kt) {
#pragma unroll
        for (int i = 0; i < 4; i++) {
            const float* pa = A + (size_t)(m0 + r0 + 32 * i) * K + kt * 32 + kq * 4;
            f32x4 v = *(const f32x4*)pa;
            if constexpr (ASUM) {
                const float* pa2 = A2 + (size_t)(m0 + r0 + 32 * i) * K + kt * 32 + kq * 4;
                f32x4 v2 = *(const f32x4*)pa2;
                v = v + v2;
            }
            ar[i] = v;
            const float* pw = W + (size_t)(n0 + r0 + 32 * i) * K + kt * 32 + kq * 4;
            wr_[i] = *(const f32x4*)pw;
        }
    };

    const int nK = K >> 5;
    loadTiles(0);
    for (int kt = 0; kt < nK; ++kt) {
#pragma unroll
        for (int i = 0; i < 4; i++) {
            int row = r0 + 32 * i;
            u16x4 ua, uw;
#pragma unroll
            for (int j = 0; j < 4; j++) { ua[j] = f2bf(ar[i][j]); uw[j] = f2bf(wr_[i][j]); }
            *(u16x4*)&As[row * 40 + kq * 4] = ua;
            *(u16x4*)&Ws[row * 40 + kq * 4] = uw;
        }
        __syncthreads();
        if (kt + 1 < nK) loadTiles(kt + 1);
        bf16x8 af[4], bf[4];
#pragma unroll
        for (int mi = 0; mi < 4; mi++)
            af[mi] = *(const bf16x8*)&As[(wm + mi * 16 + lr) * 40 + kg * 8];
#pragma unroll
        for (int ni = 0; ni < 4; ni++)
            bf[ni] = *(const bf16x8*)&Ws[(wn + ni * 16 + lr) * 40 + kg * 8];
#pragma unroll
        for (int mi = 0; mi < 4; mi++)
#pragma unroll
            for (int ni = 0; ni < 4; ni++)
                acc[mi][ni] = __builtin_amdgcn_mfma_f32_16x16x32_bf16(af[mi], bf[ni], acc[mi][ni], 0, 0, 0);
        __syncthreads();
    }

#pragma unroll
    for (int mi = 0; mi < 4; mi++)
#pragma unroll
        for (int ni = 0; ni < 4; ni++)
#pragma unroll
            for (int j = 0; j < 4; j++) {
                int m = m0 + wm + mi * 16 + kg * 4 + j;
                int n = n0 + wn + ni * 16 + lr;
                float v = acc[mi][ni][j];
                if constexpr (EPI == 1) {
                    int rr = m % LL;
                    int t = rr / 196, p = rr % 196;
                    v += bias[n] + pos[p * EE + n] + tpos[t * EE + n];
                } else if constexpr (EPI == 2) {
                    v += bias[n];
                    v = fmaxf(v, 0.f);
                }
                C[(size_t)m * ldc + n] = v;
            }
}

// ---------------- importance logits + sigmoid scale ----------------
__global__ __launch_bounds__(64) void k_logits(const float* __restrict__ h1, const float* __restrict__ w2,
                                               const float* __restrict__ b2, float* __restrict__ xseq,
                                               float* __restrict__ logits_out) {
    int row = blockIdx.x;
    int lane = threadIdx.x;
    float acc = 0.f;
#pragma unroll
    for (int i = 0; i < 6; i++) {
        int e = lane + i * 64;
        acc += h1[(size_t)row * EE + e] * w2[e];
    }
#pragma unroll
    for (int off = 32; off >= 1; off >>= 1) acc += __shfl_xor(acc, off);
    float logit = acc + b2[0];
    if (lane == 0) logits_out[row] = logit;
    float sg = 1.f / (1.f + __expf(-logit));
#pragma unroll
    for (int i = 0; i < 6; i++) {
        int e = lane + i * 64;
        xseq[(size_t)row * EE + e] *= sg;
    }
}

// ---------------- residual add + rmsnorm ----------------
__global__ __launch_bounds__(256) void k_norm(const float* __restrict__ hidden, float* __restrict__ resid,
                                              const float* __restrict__ wn, float* __restrict__ outp,
                                              int first, int writeResid) {
    int row = blockIdx.x * 4 + (threadIdx.x >> 6);
    int lane = threadIdx.x & 63;
    size_t base = (size_t)row * EE;
    float v[6];
    float ss = 0.f;
#pragma unroll
    for (int i = 0; i < 6; i++) {
        int e = lane + i * 64;
        float h = hidden[base + e];
        float r = first ? 0.f : resid[base + e];
        float s = h + r;
        v[i] = s;
        ss += s * s;
    }
#pragma unroll
    for (int off = 32; off >= 1; off >>= 1) ss += __shfl_xor(ss, off);
    if (writeResid) {
#pragma unroll
        for (int i = 0; i < 6; i++) resid[base + lane + i * 64] = v[i];
    }
    float sc = rsqrtf(ss * (1.f / 384.f) + 1e-5f);
#pragma unroll
    for (int i = 0; i < 6; i++) {
        int e = lane + i * 64;
        outp[base + e] = v[i] * sc * wn[e];
    }
}

// ---------------- fused conv1d+silu -> dbc -> dt (per 8-token tile, both dirs) ----------------
__global__ __launch_bounds__(256) void k_convdt(
    const float* __restrict__ xz,
    const float* __restrict__ cw_f, const float* __restrict__ cb_f,
    const float* __restrict__ xpw_f, const float* __restrict__ dtw_f, const float* __restrict__ dtb_f,
    const float* __restrict__ cw_b, const float* __restrict__ cb_b,
    const float* __restrict__ xpw_b, const float* __restrict__ dtw_b, const float* __restrict__ dtb_b,
    float* __restrict__ dtbuf, float* __restrict__ Bmat, float* __restrict__ Cmat) {
    const int t0 = blockIdx.x * 8, b = blockIdx.y, dir = blockIdx.z;
    const float* cw = dir ? cw_b : cw_f;
    const float* cb = dir ? cb_b : cb_f;
    const float* xpw = dir ? xpw_b : xpw_f;
    const float* dtw = dir ? dtw_b : dtw_f;
    const float* dtb = dir ? dtb_b : dtb_f;
    const int tid = threadIdx.x;
    const size_t xzb = (size_t)b * LL * 1536;

    __shared__ float xt_s[768 * 8];
    __shared__ float part_s[56 * 4 * 8];
    __shared__ float dbc_s[8 * 24];

    for (int d = tid; d < 768; d += 256) {
        float wv0 = cw[d * 4 + 0], wv1 = cw[d * 4 + 1], wv2 = cw[d * 4 + 2], wv3 = cw[d * 4 + 3];
        float bv = cb[d];
        float xw[11];
#pragma unroll
        for (int s = 0; s < 11; ++s) {
            int tt = t0 + s - 3;
            xw[s] = (tt >= 0 && tt < LL) ? xz[xzb + (size_t)(dir ? (LL - 1 - tt) : tt) * 1536 + d] : 0.f;
        }
#pragma unroll
        for (int j = 0; j < 8; j++) {
            float v = wv0 * xw[j] + wv1 * xw[j + 1] + wv2 * xw[j + 2] + wv3 * xw[j + 3] + bv;
            xt_s[d * 8 + j] = silu_f(v);
        }
    }
    __syncthreads();
    if (tid < 224) {
        int e = tid >> 2, q = tid & 3;
        const float* wrow = xpw + e * 768 + q * 192;
        const float* xs = &xt_s[q * 192 * 8];
        float acc[8];
#pragma unroll
        for (int j = 0; j < 8; j++) acc[j] = 0.f;
        for (int dd = 0; dd < 192; ++dd) {
            float w = wrow[dd];
            f32x4 x0 = *(const f32x4*)(xs + dd * 8);
            f32x4 x1 = *(const f32x4*)(xs + dd * 8 + 4);
            acc[0] += w * x0[0]; acc[1] += w * x0[1]; acc[2] += w * x0[2]; acc[3] += w * x0[3];
            acc[4] += w * x1[0]; acc[5] += w * x1[1]; acc[6] += w * x1[2]; acc[7] += w * x1[3];
        }
#pragma unroll
        for (int j = 0; j < 8; j++) part_s[(e * 4 + q) * 8 + j] = acc[j];
    }
    __syncthreads();
    for (int idx = tid; idx < 448; idx += 256) {
        int e = idx >> 3, tok = idx & 7;
        float v = part_s[(e * 4 + 0) * 8 + tok] + part_s[(e * 4 + 1) * 8 + tok] +
                  part_s[(e * 4 + 2) * 8 + tok] + part_s[(e * 4 + 3) * 8 + tok];
        size_t rbase = ((size_t)dir * BB + b) * LL + (t0 + tok);
        if (e < 24) dbc_s[tok * 24 + e] = v;
        else if (e < 40) Bmat[rbase * 16 + (e - 24)] = v;
        else Cmat[rbase * 16 + (e - 40)] = v;
    }
    __syncthreads();
    for (int d = tid; d < 768; d += 256) {
        const float* wr = dtw + d * 24;
        float wv[24];
#pragma unroll
        for (int r = 0; r < 24; r++) wv[r] = wr[r];
        float bias = dtb[d];
#pragma unroll
        for (int tok = 0; tok < 8; ++tok) {
            float acc = bias;
#pragma unroll
            for (int r = 0; r < 24; r++) acc += dbc_s[tok * 24 + r] * wv[r];
            float sp = (acc > 20.f) ? acc : log1pf(__expf(acc));
            dtbuf[(((size_t)dir * BB + b) * LL + (t0 + tok)) * 768 + d] = sp;
        }
    }
}

// ---------------- chunked 2-pass selective scan (conv recomputed on the fly) ----------------
__global__ __launch_bounds__(256) void k_scan(
    const float* __restrict__ xz, const float* __restrict__ dtbuf,
    const float* __restrict__ Bmat, const float* __restrict__ Cmat,
    const float* __restrict__ Alog_f, const float* __restrict__ Alog_b,
    const float* __restrict__ Dp_f, const float* __restrict__ Dp_b,
    const float* __restrict__ cw_f, const float* __restrict__ cw_b,
    const float* __restrict__ cb_f, const float* __restrict__ cb_b,
    float* __restrict__ ybuf) {
    const int tid = threadIdx.x;
    const int g = tid & 7, c = tid >> 3;
    const int d = blockIdx.x * 8 + g;
    const int b = blockIdx.y, dir = blockIdx.z;
    const float* Alog = dir ? Alog_b : Alog_f;
    const float* Dp = dir ? Dp_b : Dp_f;
    const float* cw = dir ? cw_b : cw_f;
    const float* cb = dir ? cb_b : cb_f;
    const int t0 = c * 49;

    __shared__ float Ssh[256][16];
    __shared__ float sdt_sh[256];
    __shared__ float Alds[8][16];

    float an[16];
#pragma unroll
    for (int n = 0; n < 16; n++) an[n] = -__expf(Alog[d * 16 + n]) * 1.44269504f;
    bool unif = (an[0] != 0.f);
#pragma unroll
    for (int n = 1; n < 16; n++) {
        float r = an[n] / an[0];
        unif = unif && (fabsf(r - (float)(n + 1)) < 1e-3f);
    }
    if (c == 0) {
#pragma unroll
        for (int n = 0; n < 16; n++) Alds[g][n] = an[n];
    }
    float cw0 = cw[d * 4 + 0], cw1 = cw[d * 4 + 1], cw2 = cw[d * 4 + 2], cw3 = cw[d * 4 + 3];
    float cbv = cb[d];
    float Dd = Dp[d];

    const size_t xzb = (size_t)b * LL * 1536;
    const size_t dbase = ((size_t)dir * BB + b) * LL;

    auto xcl = [&](int s) -> float {
        if (s < 0) return 0.f;
        return xz[xzb + (size_t)(dir ? (LL - 1 - s) : s) * 1536 + d];
    };

    float S[16];
#pragma unroll
    for (int n = 0; n < 16; n++) S[n] = 0.f;
    float sumdt = 0.f;
    float w1 = xcl(t0 - 3), w2 = xcl(t0 - 2), w3 = xcl(t0 - 1);

    // ---- pass 1 ----
    for (int s = 0; s < 49; ++s) {
        int t = t0 + s;
        float xn = xcl(t);
        float conv = cw0 * w1 + cw1 * w2 + cw2 * w3 + cw3 * xn + cbv;
        w1 = w2; w2 = w3; w3 = xn;
        float xt = silu_f(conv);
        float dtv = dtbuf[(dbase + t) * 768 + d];
        sumdt += dtv;
        float dtx = dtv * xt;
        const f32x4* Bp = (const f32x4*)(Bmat + (dbase + t) * 16);
        f32x4 Bq[4] = {Bp[0], Bp[1], Bp[2], Bp[3]};
        if (unif) {
            float p = exp2f(dtv * an[0]);
            float e = p;
#pragma unroll
            for (int n = 0; n < 16; n++) {
                S[n] = S[n] * e + dtx * Bq[n >> 2][n & 3];
                e *= p;
            }
        } else {
#pragma unroll
            for (int n = 0; n < 16; n++) {
                float e = exp2f(dtv * an[n]);
                S[n] = S[n] * e + dtx * Bq[n >> 2][n & 3];
            }
        }
    }
#pragma unroll
    for (int n = 0; n < 16; n++) Ssh[tid][n] = S[n];
    sdt_sh[tid] = sumdt;
    __syncthreads();

    // ---- combine ----
    if (tid < 128) {
        int g2 = tid >> 4, n2 = tid & 15;
        float a2 = Alds[g2][n2];
        float H = 0.f;
        for (int c2 = 0; c2 < 32; c2++) {
            int idx = c2 * 8 + g2;
            float P = exp2f(a2 * sdt_sh[idx]);
            float tmp = Ssh[idx][n2];
            Ssh[idx][n2] = H;
            H = H * P + tmp;
        }
    }
    __syncthreads();

    // ---- pass 2 ----
#pragma unroll
    for (int n = 0; n < 16; n++) S[n] = Ssh[tid][n];
    w1 = xcl(t0 - 3); w2 = xcl(t0 - 2); w3 = xcl(t0 - 1);
    for (int s = 0; s < 49; ++s) {
        int t = t0 + s;
        float xn = xcl(t);
        float conv = cw0 * w1 + cw1 * w2 + cw2 * w3 + cw3 * xn + cbv;
        w1 = w2; w2 = w3; w3 = xn;
        float xt = silu_f(conv);
        float dtv = dtbuf[(dbase + t) * 768 + d];
        float dtx = dtv * xt;
        const f32x4* Bp = (const f32x4*)(Bmat + (dbase + t) * 16);
        f32x4 Bq[4] = {Bp[0], Bp[1], Bp[2], Bp[3]};
        const f32x4* Cp = (const f32x4*)(Cmat + (dbase + t) * 16);
        f32x4 Cq[4] = {Cp[0], Cp[1], Cp[2], Cp[3]};
        float y = 0.f;
        if (unif) {
            float p = exp2f(dtv * an[0]);
            float e = p;
#pragma unroll
            for (int n = 0; n < 16; n++) {
                S[n] = S[n] * e + dtx * Bq[n >> 2][n & 3];
                y += S[n] * Cq[n >> 2][n & 3];
                e *= p;
            }
        } else {
#pragma unroll
            for (int n = 0; n < 16; n++) {
                float e = exp2f(dtv * an[n]);
                S[n] = S[n] * e + dtx * Bq[n >> 2][n & 3];
                y += S[n] * Cq[n >> 2][n & 3];
            }
        }
        y += xt * Dd;
        int pt = dir ? (LL - 1 - t) : t;
        float zv = xz[xzb + (size_t)pt * 1536 + 768 + d];
        ybuf[(dbase - (size_t)dir * BB * LL + (size_t)dir * BB * LL + 0) * 0 + (((size_t)dir * BB + b) * LL + pt) * 768 + d] = y * silu_f(zv);
    }
}

// ---------------- launcher ----------------
extern "C" void kernel_launch(void* const* d_in, const int* in_sizes, int n_in,
                              void* d_out, int out_size, void* d_ws, size_t ws_size,
                              hipStream_t stream) {
    const float* x        = (const float*)d_in[0];
    const float* patch_w  = (const float*)d_in[1];
    const float* patch_b  = (const float*)d_in[2];
    const float* pos_emb  = (const float*)d_in[3];
    const float* tpos     = (const float*)d_in[4];
    const float* imp_w1   = (const float*)d_in[5];
    const float* imp_b1   = (const float*)d_in[6];
    const float* imp_w2   = (const float*)d_in[7];
    const float* imp_b2   = (const float*)d_in[8];
    const float* in_w     = (const float*)d_in[9];
    const float* out_w    = (const float*)d_in[10];
    const float* norm_w   = (const float*)d_in[11];
    const float* norm_f_w = (const float*)d_in[12];
    const float* conv_w   = (const float*)d_in[13];
    const float* conv_b   = (const float*)d_in[14];
    const float* xp_w     = (const float*)d_in[15];
    const float* dt_w     = (const float*)d_in[16];
    const float* dt_b     = (const float*)d_in[17];
    const float* A_log    = (const float*)d_in[18];
    const float* Dp       = (const float*)d_in[19];
    const float* conv_w_b = (const float*)d_in[20];
    const float* conv_b_b = (const float*)d_in[21];
    const float* xp_w_b   = (const float*)d_in[22];
    const float* dt_w_b   = (const float*)d_in[23];
    const float* dt_b_b   = (const float*)d_in[24];
    const float* A_log_b  = (const float*)d_in[25];
    const float* D_b      = (const float*)d_in[26];

    float* out = (float*)d_out;
    float* ws = (float*)d_ws;

    float* ybuf    = ws;                    // 2*4816896 (also: patches at [0], h1 at [4816896])
    float* patches = ws;
    float* h1      = ws + 4816896;
    float* hidden  = ws + 9633792;          // 2408448
    float* resid   = hidden + 2408448;
    float* hn      = resid + 2408448;
    float* xz      = hn + 2408448;          // 9633792
    float* dtbuf   = xz + 9633792;          // 9633792
    float* Bm      = dtbuf + 9633792;       // 200704
    float* Cm      = Bm + 200704;           // 200704
    float* logits_out = out + 2408448;

    k_patch<<<6272, 256, 0, stream>>>(x, patches);
    k_gemm<1, false><<<dim3(3, 49), 256, 0, stream>>>(patches, nullptr, patch_w, hidden, 768, 384,
                                                      patch_b, pos_emb, tpos);
    k_gemm<2, false><<<dim3(3, 49), 256, 0, stream>>>(hidden, nullptr, imp_w1, h1, 384, 384,
                                                      imp_b1, nullptr, nullptr);
    k_logits<<<6272, 64, 0, stream>>>(h1, imp_w2, imp_b2, hidden, logits_out);

    for (int l = 0; l < 24; ++l) {
        k_norm<<<1568, 256, 0, stream>>>(hidden, resid, norm_w + l * 384, hn, (l == 0) ? 1 : 0, 1);
        k_gemm<0, false><<<dim3(12, 49), 256, 0, stream>>>(hn, nullptr, in_w + (size_t)l * 589824, xz,
                                                           384, 1536, nullptr, nullptr, nullptr);
        k_convdt<<<dim3(196, 4, 2), 256, 0, stream>>>(
            xz,
            conv_w + l * 3072, conv_b + l * 768, xp_w + l * 43008, dt_w + l * 18432, dt_b + l * 768,
            conv_w_b + l * 3072, conv_b_b + l * 768, xp_w_b + l * 43008, dt_w_b + l * 18432, dt_b_b + l * 768,
            dtbuf, Bm, Cm);
        k_scan<<<dim3(96, 4, 2), 256, 0, stream>>>(
            xz, dtbuf, Bm, Cm,
            A_log + l * 12288, A_log_b + l * 12288,
            Dp + l * 768, D_b + l * 768,
            conv_w + l * 3072, conv_w_b + l * 3072,
            conv_b + l * 768, conv_b_b + l * 768,
            ybuf);
        k_gemm<0, true><<<dim3(3, 49), 256, 0, stream>>>(ybuf, ybuf + 4816896,
                                                         out_w + (size_t)l * 294912, hidden,
                                                         768, 384, nullptr, nullptr, nullptr);
    }
    k_norm<<<1568, 256, 0, stream>>>(hidden, resid, norm_f_w, out, 0, 0);
}